// Round 11
// baseline (336.485 us; speedup 1.0000x reference)
//
#include <hip/hip_runtime.h>

typedef unsigned short ushort_t;
typedef __bf16 bf16x8 __attribute__((ext_vector_type(8)));
typedef float f32x4 __attribute__((ext_vector_type(4)));
typedef short short8 __attribute__((ext_vector_type(8)));

#define SBAR()   asm volatile("s_barrier" ::: "memory")
#define WAITV0() asm volatile("s_waitcnt vmcnt(0)" ::: "memory")
#define WAITV4() asm volatile("s_waitcnt vmcnt(4)" ::: "memory")
#define WAITV6() asm volatile("s_waitcnt vmcnt(6)" ::: "memory")
#define WAITV8() asm volatile("s_waitcnt vmcnt(8)" ::: "memory")
#define WAITL0() asm volatile("s_waitcnt lgkmcnt(0)" ::: "memory")

__device__ __forceinline__ float bf2f(unsigned short u) {
    union { unsigned int i; float f; } v; v.i = ((unsigned int)u) << 16; return v.f;
}
__device__ __forceinline__ unsigned short f2bf(float f) {
    union { float f; unsigned int i; } v; v.f = f;
    unsigned int r = v.i + 0x7fffu + ((v.i >> 16) & 1u);
    return (unsigned short)(r >> 16);
}
__device__ __forceinline__ float sigm(float x) { return 1.0f / (1.0f + __expf(-x)); }

__device__ __forceinline__ void async_copy16(const ushort_t* src, ushort_t* dst_lds) {
    __builtin_amdgcn_global_load_lds(
        (const __attribute__((address_space(1))) void*)src,
        (__attribute__((address_space(3))) void*)dst_lds,
        16, 0, 0);
}

// 8 f32 -> short8 of bf16 (RNE via native cast; compiler may fuse to v_cvt_pk_bf16_f32)
__device__ __forceinline__ short8 cvt8(float4 x, float4 y) {
    bf16x8 h;
    h[0] = (__bf16)x.x; h[1] = (__bf16)x.y; h[2] = (__bf16)x.z; h[3] = (__bf16)x.w;
    h[4] = (__bf16)y.x; h[5] = (__bf16)y.y; h[6] = (__bf16)y.z; h[7] = (__bf16)y.w;
    return __builtin_bit_cast(short8, h);
}

// ---- param conversion: 5 W (768x768) + 5 bias (768) + ts (768), f32 -> bf16 ----
#define WSEG 589824           // 768*768
#define NWALL 2949120         // 5*WSEG
#define NTOT 2953728          // + 6*768
__global__ __launch_bounds__(256)
void convert_params(const float* __restrict__ Wq, const float* __restrict__ Wk,
                    const float* __restrict__ Wv, const float* __restrict__ Wg1,
                    const float* __restrict__ Wg2, const float* __restrict__ bq,
                    const float* __restrict__ bk, const float* __restrict__ bv,
                    const float* __restrict__ bg1, const float* __restrict__ bg2,
                    const float* __restrict__ ts, ushort_t* __restrict__ dst)
{
    int i = (blockIdx.x * 256 + threadIdx.x) * 8;
    if (i >= NTOT) return;
    const float* src; int off;
    if (i < NWALL) {
        int wi = i / WSEG; off = i - wi * WSEG;
        src = (wi == 0) ? Wq : (wi == 1) ? Wk : (wi == 2) ? Wv : (wi == 3) ? Wg1 : Wg2;
    } else {
        int j = i - NWALL; int bi = j / 768; off = j - bi * 768;
        src = (bi == 0) ? bq : (bi == 1) ? bk : (bi == 2) ? bv : (bi == 3) ? bg1 : (bi == 4) ? bg2 : ts;
    }
    float4 a = *(const float4*)(src + off);
    float4 b = *(const float4*)(src + off + 4);
    *(short8*)(dst + i) = cvt8(a, b);
}

// ---- finalize: rinv[row] = 1 / sum_{b<nb} psums[row*nb+b] ----
__global__ __launch_bounds__(256)
void finalize_rinv(const float* __restrict__ psums, float* __restrict__ rinv, int nb)
{
    int row = blockIdx.x * 256 + threadIdx.x;
    const float* p = psums + (size_t)row * nb;
    float s = 0.f;
    for (int i = 0; i < nb; ++i) s += p[i];
    rinv[row] = 1.0f / s;
}

// C[M,N] = A[M,K] @ B[N,K]^T (+ epilogue), optionally batched (M = rows per batch).
// B bf16 via global_load_lds (2-deep, 3 buf). A: bf16 gload_lds (AF32=0) or f32 reg-staged
// with conflict-free linear ds_write + native bf16 cvt (AF32=1; requires K%64==0).
// CF32: f32 store. QKV: gridDim.z=3; bz selects A f32 ptr {Af0,Af1,Af2} and dest; bias+bz*768.
// EPI: 0=plain, 1=+bias, 3=+bias+relu, 4=gate sigmoid(sigmoid(x+bias))*aux*ts,
//      5=exp(x*scale) + per-block row partials -> psum_out, 7=multiply by rinvg[bz*M+row]
// Requires gridDim.x*gridDim.y*gridDim.z % 8 == 0, K%32==0, K>=96.
template<int EPI, int CF32, int QKV, int AF32>
__global__ __launch_bounds__(256, 2)
void gemm_bt(const void* __restrict__ Av, const void* __restrict__ Af1,
             const void* __restrict__ Af2, const ushort_t* __restrict__ B,
             void* __restrict__ Cv, void* __restrict__ Cv2,
             const ushort_t* __restrict__ bias,
             const ushort_t* __restrict__ aux, const ushort_t* __restrict__ ts,
             const float* __restrict__ rinvg, float* __restrict__ psum_out,
             int M, int N, int K, float scale,
             long long batchA, long long batchB, long long batchC)
{
    __shared__ __align__(16) ushort_t As[3][128 * 32];
    __shared__ __align__(16) ushort_t Bs[3][128 * 32];
    __shared__ float rsmx[256];
    const int tid  = threadIdx.x;
    const int lane = tid & 63;
    const int wave = tid >> 6;
    const int wr = wave >> 1, wc = wave & 1;

    // XCD-aware bijective swizzle over the full flat grid (nwg % 8 == 0)
    const int gx = gridDim.x, gy = gridDim.y;
    const int nwg = gx * gy * gridDim.z;
    int fid = (blockIdx.z * gy + blockIdx.y) * gx + blockIdx.x;
    fid = (fid & 7) * (nwg >> 3) + (fid >> 3);
    const int bz  = fid / (gx * gy);
    const int rem = fid - bz * (gx * gy);
    const int by  = rem / gx;
    const int bx  = rem - by * gx;
    const int row0 = by * 128;
    const int col0 = bx * 128;

    f32x4 acc[4][4] = {};

    const int srow = tid >> 2;
    const int scol = (tid & 3) * 8;
    const ushort_t* ga0 = (const ushort_t*)Av + batchA * bz + (size_t)(row0 + srow) * K + scol;
    const ushort_t* gb0 = B + batchB * bz + (size_t)(col0 + srow) * K + scol;

    const int kop  = (lane >> 4) * 8;
    const int arow = wr * 64 + (lane & 15);
    const int brow = wc * 64 + (lane & 15);

    const int NT = K >> 5;

#define MFMA_STEP(AC, BC) do { \
    bf16x8 af_[4], bf_[4]; \
    _Pragma("unroll") \
    for (int m = 0; m < 4; ++m) af_[m] = *(const bf16x8*)((AC) + (arow + m * 16) * 32 + kop); \
    _Pragma("unroll") \
    for (int n = 0; n < 4; ++n) bf_[n] = *(const bf16x8*)((BC) + (brow + n * 16) * 32 + kop); \
    _Pragma("unroll") \
    for (int m = 0; m < 4; ++m) \
        _Pragma("unroll") \
        for (int n = 0; n < 4; ++n) \
            acc[m][n] = __builtin_amdgcn_mfma_f32_16x16x32_bf16(af_[m], bf_[n], acc[m][n], 0, 0, 0); \
} while (0)

    if (AF32) {
        // f32 A: thread t owns LDS slot t*16B (linear, conflict-free) = row t>>2, cols (t&3)*8..+7
        const float* gAf = (bz == 0) ? (const float*)Av : (bz == 1) ? (const float*)Af1
                                                        : (const float*)Af2;
        const float* gA  = gAf + (size_t)(row0 + srow) * K + scol;
        const float* gA2 = gA + (size_t)64 * K;

#define STAGEB2(T, BUF) do { const int kk_ = (T) * 32; \
    async_copy16(gb0 + kk_,                  &Bs[BUF][0] + tid * 8); \
    async_copy16(gb0 + (size_t)64 * K + kk_, &Bs[BUF][0] + 2048 + tid * 8); } while (0)

        STAGEB2(0, 0);
        STAGEB2(1, 1);
        float4 pa0 = *(const float4*)(gA);      float4 pa1 = *(const float4*)(gA + 4);
        float4 pa2 = *(const float4*)(gA2);     float4 pa3 = *(const float4*)(gA2 + 4);
        float4 qa0, qa1, qa2, qa3;

        for (int t = 0; t < NT; t += 2) {
            // ---- even sub-step t: regs pa*, A-buf 0
            if (t + 2 < NT) STAGEB2(t + 2, (t + 2) % 3);
            if (t + 1 < NT) {
                const int k1 = (t + 1) * 32;
                qa0 = *(const float4*)(gA + k1);  qa1 = *(const float4*)(gA + k1 + 4);
                qa2 = *(const float4*)(gA2 + k1); qa3 = *(const float4*)(gA2 + k1 + 4);
            }
            if (t + 2 < NT)      WAITV6();   // retire A(t) regs + B(t); B(t+2),A(t+1) fly
            else if (t + 1 < NT) WAITV4();
            else                 WAITV0();
            *(short8*)(&As[0][0] + tid * 8)        = cvt8(pa0, pa1);
            *(short8*)(&As[0][0] + 2048 + tid * 8) = cvt8(pa2, pa3);
            WAITL0();
            SBAR();
            MFMA_STEP(&As[0][0], &Bs[0][0] + (t % 3) * 4096);
            SBAR();
            // ---- odd sub-step t+1: regs qa*, A-buf 1
            const int t1 = t + 1;
            if (t1 + 2 < NT) STAGEB2(t1 + 2, (t1 + 2) % 3);
            if (t1 + 1 < NT) {
                const int k1 = (t1 + 1) * 32;
                pa0 = *(const float4*)(gA + k1);  pa1 = *(const float4*)(gA + k1 + 4);
                pa2 = *(const float4*)(gA2 + k1); pa3 = *(const float4*)(gA2 + k1 + 4);
            }
            if (t1 + 2 < NT)      WAITV6();
            else if (t1 + 1 < NT) WAITV4();
            else                  WAITV0();
            *(short8*)(&As[1][0] + tid * 8)        = cvt8(qa0, qa1);
            *(short8*)(&As[1][0] + 2048 + tid * 8) = cvt8(qa2, qa3);
            WAITL0();
            SBAR();
            MFMA_STEP(&As[1][0], &Bs[0][0] + (t1 % 3) * 4096);
            SBAR();
        }
#undef STAGEB2
    } else {
#define STAGE4(T, BUF) do { const int kk_ = (T) * 32; \
    async_copy16(ga0 + kk_,                  &As[BUF][0] + tid * 8); \
    async_copy16(ga0 + (size_t)64 * K + kk_, &As[BUF][0] + 2048 + tid * 8); \
    async_copy16(gb0 + kk_,                  &Bs[BUF][0] + tid * 8); \
    async_copy16(gb0 + (size_t)64 * K + kk_, &Bs[BUF][0] + 2048 + tid * 8); \
} while (0)

        STAGE4(0, 0);
        STAGE4(1, 1);

        int cur = 0;
        for (int t = 0; t < NT; ++t) {
            if (t + 2 < NT) {
                int nb = cur + 2; if (nb >= 3) nb -= 3;
                STAGE4(t + 2, nb);
                WAITV8();
            } else if (t + 1 < NT) {
                WAITV4();
            } else {
                WAITV0();
            }
            SBAR();
            MFMA_STEP(&As[0][0] + cur * 4096, &Bs[0][0] + cur * 4096);
            SBAR();
            ++cur; if (cur >= 3) cur = 0;
        }
#undef STAGE4
    }
#undef MFMA_STEP

    // epilogue: C/D layout col=lane&15, row=(lane>>4)*4+reg
    const int r0 = row0 + wr * 64 + (lane >> 4) * 4;
    const int c0 = col0 + wc * 64 + (lane & 15);

    float rv[4][4];
    if (EPI == 7) {
        #pragma unroll
        for (int m = 0; m < 4; ++m)
            #pragma unroll
            for (int r = 0; r < 4; ++r)
                rv[m][r] = rinvg[(size_t)bz * M + r0 + m * 16 + r];
    }
    float rsum[4][4] = {};

    ushort_t* Cb = (QKV && bz == 2) ? (ushort_t*)Cv2 : (ushort_t*)Cv + batchC * bz;
    float* Cf = (float*)Cv;
    #pragma unroll
    for (int m = 0; m < 4; ++m) {
        #pragma unroll
        for (int n = 0; n < 4; ++n) {
            const int col = c0 + n * 16;
            #pragma unroll
            for (int r = 0; r < 4; ++r) {
                const int row = r0 + m * 16 + r;
                float val = acc[m][n][r];
                if (EPI == 1) {
                    val += bf2f(bias[(QKV ? bz * 768 : 0) + col]);
                } else if (EPI == 3) {
                    val += bf2f(bias[col]);
                    val = fmaxf(val, 0.0f);
                } else if (EPI == 4) {
                    val += bf2f(bias[col]);
                    float g  = sigm(val);
                    float gg = sigm(g);
                    val = gg * bf2f(aux[(size_t)row * N + col]) * bf2f(ts[col]);
                } else if (EPI == 5) {
                    val = __expf(val * scale);
                    rsum[m][r] += val;
                } else if (EPI == 7) {
                    val *= rv[m][r];
                }
                if (CF32) Cf[(size_t)row * N + col] = val;
                else      Cb[(size_t)row * N + col] = f2bf(val);
            }
        }
    }

    if (EPI == 5) {
        #pragma unroll
        for (int m = 0; m < 4; ++m)
            #pragma unroll
            for (int r = 0; r < 4; ++r) {
                float s = rsum[m][r];
                s += __shfl_xor(s, 1);
                s += __shfl_xor(s, 2);
                s += __shfl_xor(s, 4);
                s += __shfl_xor(s, 8);
                rsum[m][r] = s;
            }
        if ((lane & 15) == 0) {
            const int quad = lane >> 4;
            #pragma unroll
            for (int m = 0; m < 4; ++m)
                #pragma unroll
                for (int r = 0; r < 4; ++r)
                    rsmx[(wr * 64 + m * 16 + quad * 4 + r) * 2 + wc] = rsum[m][r];
        }
        __syncthreads();
        if (tid < 128) {
            float s = rsmx[tid * 2] + rsmx[tid * 2 + 1];
            psum_out[((size_t)bz * M + row0 + tid) * gx + bx] = s;
        }
    }
}

// VT[z][c][r] = V[z][r][c];  grid (C/32, R/32, Z), block (32,8). bf16.
__global__ __launch_bounds__(256)
void transpose2d(const ushort_t* __restrict__ V, ushort_t* __restrict__ VT, int R, int Ccols)
{
    __shared__ ushort_t t[32][33];
    const size_t zoff = (size_t)blockIdx.z * R * Ccols;
    const int tx = threadIdx.x, ty = threadIdx.y;
    const int c = blockIdx.x * 32 + tx;
    const int rbase = blockIdx.y * 32;
    #pragma unroll
    for (int i = 0; i < 4; ++i)
        t[ty + i * 8][tx] = V[zoff + (size_t)(rbase + ty + i * 8) * Ccols + c];
    __syncthreads();
    const int r = rbase + tx;
    const int cbase = blockIdx.x * 32;
    #pragma unroll
    for (int i = 0; i < 4; ++i)
        VT[zoff + (size_t)(cbase + ty + i * 8) * R + r] = t[tx][ty + i * 8];
}

extern "C" void kernel_launch(void* const* d_in, const int* in_sizes, int n_in,
                              void* d_out, int out_size, void* d_ws, size_t ws_size,
                              hipStream_t stream)
{
    (void)in_sizes; (void)n_in; (void)out_size; (void)ws_size;
    const float* query = (const float*)d_in[0];
    const float* key_  = (const float*)d_in[1];
    const float* value = (const float*)d_in[2];
    const float* Wq  = (const float*)d_in[3];
    const float* bq  = (const float*)d_in[4];
    const float* Wk  = (const float*)d_in[5];
    const float* bk  = (const float*)d_in[6];
    const float* Wv  = (const float*)d_in[7];
    const float* bv  = (const float*)d_in[8];
    const float* Wg1 = (const float*)d_in[9];
    const float* bg1 = (const float*)d_in[10];
    const float* Wg2 = (const float*)d_in[11];
    const float* bg2 = (const float*)d_in[12];
    const float* tsc = (const float*)d_in[13];

    const int S = 2048, D = 768, Bc = 8;
    const int MS = Bc * S;                     // 16384
    const long long SD = (long long)S * D;     // 1,572,864
    const long long SS = (long long)S * S;     // 4,194,304
    const long long MSD = (long long)MS * D;   // 12,582,912

    // ws layout (bytes):
    //   q/att @0 (24MiB) | k/rinv/h @24MiB | vT @48MiB | P @72MiB (64MiB) | Wb @136MiB
    //   rinv (64KB) overlays k (k dead after scores); psums (2MB f32) parked in d_out
    char* ws = (char*)d_ws;
    ushort_t* q    = (ushort_t*)(ws);
    ushort_t* att  = q;                        // PV overwrites q after scores consumed it
    ushort_t* k    = (ushort_t*)(ws + 25165824ll);
    float*    rinv = (float*)(ws + 25165824ll);
    ushort_t* h    = k;
    ushort_t* vT   = (ushort_t*)(ws + 50331648ll);
    ushort_t* P    = (ushort_t*)(ws + 75497472ll);
    ushort_t* Wb   = (ushort_t*)(ws + 142606336ll);
    ushort_t* v    = (ushort_t*)d_out;         // bf16 v in front of d_out until transpose
    float*  psums  = (float*)d_out;            // 2MB, alive only between scores and finalize

    const int WQ = 0, WG1 = 1769472, WG2 = 2359296;
    const int BQ = 2949120, BG1 = 2951424, BG2 = 2952192, TSO = 2952960;

    const dim3 blk(256);
    const float scale = 0.03608439182435161f; // 1/sqrt(768)

    // 0. convert params to bf16
    convert_params<<<dim3((NTOT / 8 + 255) / 256), blk, 0, stream>>>(
        Wq, Wk, Wv, Wg1, Wg2, bq, bk, bv, bg1, bg2, tsc, Wb);
    // 1. fused QKV projections, f32 A staged in-kernel: bz=0->q, 1->k, 2->v (d_out)
    gemm_bt<1, 0, 1, 1><<<dim3(D / 128, MS / 128, 3), blk, 0, stream>>>(
        query, key_, value, Wb + WQ, q, v, Wb + BQ, nullptr, nullptr, nullptr, nullptr,
        MS, D, D, 1.f, 0, (long long)WSEG, MSD);
    // 2. vT = transpose(v) per batch; v dead afterwards
    transpose2d<<<dim3(D / 32, S / 32, Bc), dim3(32, 8), 0, stream>>>(v, vT, S, D);
    // 3. P = exp(q @ k^T * scale), + per-block row partials -> psums (d_out)
    gemm_bt<5, 0, 0, 0><<<dim3(S / 128, S / 128, Bc), blk, 0, stream>>>(
        q, nullptr, nullptr, k, P, nullptr, nullptr, nullptr, nullptr, nullptr, psums,
        S, S, D, scale, SD, SD, SS);
    // 4. rinv[row] = 1/rowsum (16 partials per row)
    finalize_rinv<<<dim3(MS / 256), blk, 0, stream>>>(psums, rinv, S / 128);
    // 5. att = (P @ vT^T) * rinv   (batched; att overlays q)
    gemm_bt<7, 0, 0, 0><<<dim3(D / 128, S / 128, Bc), blk, 0, stream>>>(
        P, nullptr, nullptr, vT, att, nullptr, nullptr, nullptr, nullptr, rinv, nullptr,
        S, D, S, 1.f, SS, SD, SD);
    // 6. h = relu(att @ Wg1^T + bg1)  (h overlays k/rinv -- rinv consumed)
    gemm_bt<3, 0, 0, 0><<<dim3(D / 128, MS / 128, 1), blk, 0, stream>>>(
        att, nullptr, nullptr, Wb + WG1, h, nullptr, Wb + BG1, nullptr, nullptr, nullptr, nullptr,
        MS, D, D, 1.f, 0, 0, 0);
    // 7. out = sigmoid(sigmoid(h @ Wg2^T + bg2)) * att * ts  (f32 -> d_out)
    gemm_bt<4, 1, 0, 0><<<dim3(D / 128, MS / 128, 1), blk, 0, stream>>>(
        h, nullptr, nullptr, Wb + WG2, d_out, nullptr, Wb + BG2, att, Wb + TSO, nullptr, nullptr,
        MS, D, D, 1.f, 0, 0, 0);
}

// Round 12
// 331.075 us; speedup vs baseline: 1.0163x; 1.0163x over previous
//
#include <hip/hip_runtime.h>

typedef unsigned short ushort_t;
typedef __bf16 bf16x8 __attribute__((ext_vector_type(8)));
typedef float f32x4 __attribute__((ext_vector_type(4)));
typedef short short8 __attribute__((ext_vector_type(8)));

#define SBAR()   asm volatile("s_barrier" ::: "memory")
#define WAITV0() asm volatile("s_waitcnt vmcnt(0)" ::: "memory")
#define WAITV4() asm volatile("s_waitcnt vmcnt(4)" ::: "memory")
#define WAITV8() asm volatile("s_waitcnt vmcnt(8)" ::: "memory")

__device__ __forceinline__ float bf2f(unsigned short u) {
    union { unsigned int i; float f; } v; v.i = ((unsigned int)u) << 16; return v.f;
}
__device__ __forceinline__ unsigned short f2bf(float f) {
    union { float f; unsigned int i; } v; v.f = f;
    unsigned int r = v.i + 0x7fffu + ((v.i >> 16) & 1u);
    return (unsigned short)(r >> 16);
}
__device__ __forceinline__ float sigm(float x) { return 1.0f / (1.0f + __expf(-x)); }

__device__ __forceinline__ void async_copy16(const ushort_t* src, ushort_t* dst_lds) {
    __builtin_amdgcn_global_load_lds(
        (const __attribute__((address_space(1))) void*)src,
        (__attribute__((address_space(3))) void*)dst_lds,
        16, 0, 0);
}

// ---- param conversion: 5 W (768x768) + 5 bias (768) + ts (768), f32 -> bf16 ----
#define WSEG 589824           // 768*768
#define NWALL 2949120         // 5*WSEG
#define NTOT 2953728          // + 6*768
__global__ __launch_bounds__(256)
void convert_params(const float* __restrict__ Wq, const float* __restrict__ Wk,
                    const float* __restrict__ Wv, const float* __restrict__ Wg1,
                    const float* __restrict__ Wg2, const float* __restrict__ bq,
                    const float* __restrict__ bk, const float* __restrict__ bv,
                    const float* __restrict__ bg1, const float* __restrict__ bg2,
                    const float* __restrict__ ts, ushort_t* __restrict__ dst)
{
    int i = (blockIdx.x * 256 + threadIdx.x) * 8;
    if (i >= NTOT) return;
    const float* src; int off;
    if (i < NWALL) {
        int wi = i / WSEG; off = i - wi * WSEG;
        src = (wi == 0) ? Wq : (wi == 1) ? Wk : (wi == 2) ? Wv : (wi == 3) ? Wg1 : Wg2;
    } else {
        int j = i - NWALL; int bi = j / 768; off = j - bi * 768;
        src = (bi == 0) ? bq : (bi == 1) ? bk : (bi == 2) ? bv : (bi == 3) ? bg1 : (bi == 4) ? bg2 : ts;
    }
    float4 a = *(const float4*)(src + off);
    float4 b = *(const float4*)(src + off + 4);
    short8 o;
    o[0] = (short)f2bf(a.x); o[1] = (short)f2bf(a.y); o[2] = (short)f2bf(a.z); o[3] = (short)f2bf(a.w);
    o[4] = (short)f2bf(b.x); o[5] = (short)f2bf(b.y); o[6] = (short)f2bf(b.z); o[7] = (short)f2bf(b.w);
    *(short8*)(dst + i) = o;
}

// ---- input conversion: query/key/value [16384x768] f32 -> bf16 into X[3] ----
#define PERT 12582912ll
__global__ __launch_bounds__(256)
void convert_inputs(const float* __restrict__ q, const float* __restrict__ k,
                    const float* __restrict__ v, ushort_t* __restrict__ X)
{
    long long i = ((long long)blockIdx.x * 256 + threadIdx.x) * 8;
    const float* src; long long off;
    if (i < PERT)          { src = q; off = i; }
    else if (i < 2 * PERT) { src = k; off = i - PERT; }
    else                   { src = v; off = i - 2 * PERT; }
    float4 a = *(const float4*)(src + off);
    float4 b = *(const float4*)(src + off + 4);
    short8 o;
    o[0] = (short)f2bf(a.x); o[1] = (short)f2bf(a.y); o[2] = (short)f2bf(a.z); o[3] = (short)f2bf(a.w);
    o[4] = (short)f2bf(b.x); o[5] = (short)f2bf(b.y); o[6] = (short)f2bf(b.z); o[7] = (short)f2bf(b.w);
    *(short8*)(X + i) = o;
}

// ---- finalize: rinv[row] = 1 / sum_{b<nb} psums[row*nb+b]; rows = grid*256 ----
__global__ __launch_bounds__(256)
void finalize_rinv(const float* __restrict__ psums, float* __restrict__ rinv, int nb)
{
    int row = blockIdx.x * 256 + threadIdx.x;
    const float* p = psums + (size_t)row * nb;
    float s = 0.f;
    for (int i = 0; i < nb; ++i) s += p[i];
    rinv[row] = 1.0f / s;
}

// C[M,N] = A[M,K] @ B[N,K]^T (+ epilogue), optionally batched (M = rows per batch).
// All-bf16 operands via global_load_lds; 3-buffer 2-deep counted-vmcnt pipeline, raw s_barrier.
// CF32: f32 store. QKV: gridDim.z=3; bz selects dest {Cv+bz*batchC | Cv2 for bz==2}, bias+bz*768.
// EPI: 0=plain, 1=+bias, 3=+bias+relu, 4=gate sigmoid(sigmoid(x+bias))*aux*ts,
//      5=exp(x*scale) + per-block row partial sums -> psum_out[bz*M+row][gridDim.x],
//      7=multiply by rinvg[bz*M+row]
// Requires gridDim.x*gridDim.y*gridDim.z % 8 == 0, K%32==0, K>=64.
template<int EPI, int CF32, int QKV>
__global__ __launch_bounds__(256, 2)
void gemm_bt(const ushort_t* __restrict__ A, const ushort_t* __restrict__ B,
             void* __restrict__ Cv, void* __restrict__ Cv2,
             const ushort_t* __restrict__ bias,
             const ushort_t* __restrict__ aux, const ushort_t* __restrict__ ts,
             const float* __restrict__ rinvg, float* __restrict__ psum_out,
             int M, int N, int K, float scale,
             long long batchA, long long batchB, long long batchC)
{
    __shared__ __align__(16) ushort_t As[3][128 * 32];
    __shared__ __align__(16) ushort_t Bs[3][128 * 32];
    __shared__ float rsmx[256];
    const int tid  = threadIdx.x;
    const int lane = tid & 63;
    const int wave = tid >> 6;
    const int wr = wave >> 1, wc = wave & 1;

    // XCD-aware bijective swizzle over the full flat grid (nwg % 8 == 0)
    const int gx = gridDim.x, gy = gridDim.y;
    const int nwg = gx * gy * gridDim.z;
    int fid = (blockIdx.z * gy + blockIdx.y) * gx + blockIdx.x;
    fid = (fid & 7) * (nwg >> 3) + (fid >> 3);
    const int bz  = fid / (gx * gy);
    const int rem = fid - bz * (gx * gy);
    const int by  = rem / gx;
    const int bx  = rem - by * gx;
    const int row0 = by * 128;
    const int col0 = bx * 128;

    f32x4 acc[4][4] = {};

    // staging: 256 threads x 16B = 64 rows of 32 bf16 per inst
    const int srow = tid >> 2;
    const int scol = (tid & 3) * 8;
    const ushort_t* ga0 = A + batchA * bz + (size_t)(row0 + srow) * K + scol;
    const ushort_t* gb0 = B + batchB * bz + (size_t)(col0 + srow) * K + scol;

    const int kop  = (lane >> 4) * 8;
    const int arow = wr * 64 + (lane & 15);
    const int brow = wc * 64 + (lane & 15);

    const int NT = K >> 5;

#define STAGE4(T, BUF) do { const int kk_ = (T) * 32; \
    async_copy16(ga0 + kk_,                  &As[BUF][0] + tid * 8); \
    async_copy16(ga0 + (size_t)64 * K + kk_, &As[BUF][0] + 2048 + tid * 8); \
    async_copy16(gb0 + kk_,                  &Bs[BUF][0] + tid * 8); \
    async_copy16(gb0 + (size_t)64 * K + kk_, &Bs[BUF][0] + 2048 + tid * 8); \
} while (0)

    STAGE4(0, 0);
    STAGE4(1, 1);

    int cur = 0;
    for (int t = 0; t < NT; ++t) {
        if (t + 2 < NT) {
            int nb = cur + 2; if (nb >= 3) nb -= 3;
            STAGE4(t + 2, nb);
            WAITV8();   // tile t landed; tiles t+1, t+2 (8 loads) in flight
        } else if (t + 1 < NT) {
            WAITV4();   // tile t landed; tile t+1 in flight
        } else {
            WAITV0();
        }
        SBAR();
        const ushort_t* Ac = &As[0][0] + cur * 4096;
        const ushort_t* Bc = &Bs[0][0] + cur * 4096;
        bf16x8 af[4], bfr[4];
        #pragma unroll
        for (int m = 0; m < 4; ++m)
            af[m] = *(const bf16x8*)(Ac + (arow + m * 16) * 32 + kop);
        #pragma unroll
        for (int n = 0; n < 4; ++n)
            bfr[n] = *(const bf16x8*)(Bc + (brow + n * 16) * 32 + kop);
        #pragma unroll
        for (int m = 0; m < 4; ++m)
            #pragma unroll
            for (int n = 0; n < 4; ++n)
                acc[m][n] = __builtin_amdgcn_mfma_f32_16x16x32_bf16(af[m], bfr[n], acc[m][n], 0, 0, 0);
        SBAR();
        ++cur; if (cur >= 3) cur = 0;
    }
#undef STAGE4

    // epilogue: C/D layout col=lane&15, row=(lane>>4)*4+reg
    const int r0 = row0 + wr * 64 + (lane >> 4) * 4;
    const int c0 = col0 + wc * 64 + (lane & 15);

    float rv[4][4];
    if (EPI == 7) {
        #pragma unroll
        for (int m = 0; m < 4; ++m)
            #pragma unroll
            for (int r = 0; r < 4; ++r)
                rv[m][r] = rinvg[(size_t)bz * M + r0 + m * 16 + r];
    }
    float rsum[4][4] = {};

    ushort_t* Cb = (QKV && bz == 2) ? (ushort_t*)Cv2 : (ushort_t*)Cv + batchC * bz;
    float* Cf = (float*)Cv;
    #pragma unroll
    for (int m = 0; m < 4; ++m) {
        #pragma unroll
        for (int n = 0; n < 4; ++n) {
            const int col = c0 + n * 16;
            #pragma unroll
            for (int r = 0; r < 4; ++r) {
                const int row = r0 + m * 16 + r;
                float val = acc[m][n][r];
                if (EPI == 1) {
                    val += bf2f(bias[(QKV ? bz * 768 : 0) + col]);
                } else if (EPI == 3) {
                    val += bf2f(bias[col]);
                    val = fmaxf(val, 0.0f);
                } else if (EPI == 4) {
                    val += bf2f(bias[col]);
                    float g  = sigm(val);
                    float gg = sigm(g);
                    val = gg * bf2f(aux[(size_t)row * N + col]) * bf2f(ts[col]);
                } else if (EPI == 5) {
                    val = __expf(val * scale);
                    rsum[m][r] += val;
                } else if (EPI == 7) {
                    val *= rv[m][r];
                }
                if (CF32) Cf[(size_t)row * N + col] = val;
                else      Cb[(size_t)row * N + col] = f2bf(val);
            }
        }
    }

    if (EPI == 5) {
        // reduce over the 16 lanes holding the wave's 16-col groups (lane bits 0..3)
        #pragma unroll
        for (int m = 0; m < 4; ++m)
            #pragma unroll
            for (int r = 0; r < 4; ++r) {
                float s = rsum[m][r];
                s += __shfl_xor(s, 1);
                s += __shfl_xor(s, 2);
                s += __shfl_xor(s, 4);
                s += __shfl_xor(s, 8);
                rsum[m][r] = s;
            }
        if ((lane & 15) == 0) {
            const int quad = lane >> 4;
            #pragma unroll
            for (int m = 0; m < 4; ++m)
                #pragma unroll
                for (int r = 0; r < 4; ++r)
                    rsmx[(wr * 64 + m * 16 + quad * 4 + r) * 2 + wc] = rsum[m][r];
        }
        __syncthreads();
        if (tid < 128) {
            float s = rsmx[tid * 2] + rsmx[tid * 2 + 1];
            psum_out[((size_t)bz * M + row0 + tid) * gx + bx] = s;
        }
    }
}

// VT[z][c][r] = V[z][r][c];  64x64 tiles, short8 both directions.
// grid (C/64, R/64, Z), block 256. R, C per-batch dims.
__global__ __launch_bounds__(256)
void transpose2d(const ushort_t* __restrict__ V, ushort_t* __restrict__ VT, int R, int Ccols)
{
    __shared__ ushort_t t[64][72];
    const size_t zoff = (size_t)blockIdx.z * R * Ccols;
    const int r0 = blockIdx.y * 64;
    const int c0 = blockIdx.x * 64;
    const int tid = threadIdx.x;

    // load: thread -> row tid>>2 (0..63), 16 cols at (tid&3)*16
    const int lr = tid >> 2;
    const int lc = (tid & 3) * 16;
    const ushort_t* src = V + zoff + (size_t)(r0 + lr) * Ccols + c0 + lc;
    short8 a = *(const short8*)(src);
    short8 b = *(const short8*)(src + 8);
    *(short8*)(&t[lr][lc])     = a;
    *(short8*)(&t[lr][lc + 8]) = b;
    __syncthreads();

    // store: thread -> out-row (orig col) tid>>2, 16 orig-rows at (tid&3)*16
    const int oc = tid >> 2;
    const int orr = (tid & 3) * 16;
    short8 o1, o2;
    #pragma unroll
    for (int j = 0; j < 8; ++j) {
        o1[j] = (short)t[orr + j][oc];
        o2[j] = (short)t[orr + 8 + j][oc];
    }
    ushort_t* dst = VT + zoff + (size_t)(c0 + oc) * R + r0 + orr;
    *(short8*)(dst)     = o1;
    *(short8*)(dst + 8) = o2;
}

extern "C" void kernel_launch(void* const* d_in, const int* in_sizes, int n_in,
                              void* d_out, int out_size, void* d_ws, size_t ws_size,
                              hipStream_t stream)
{
    (void)in_sizes; (void)n_in; (void)out_size; (void)ws_size;
    const float* query = (const float*)d_in[0];
    const float* key_  = (const float*)d_in[1];
    const float* value = (const float*)d_in[2];
    const float* Wq  = (const float*)d_in[3];
    const float* bq  = (const float*)d_in[4];
    const float* Wk  = (const float*)d_in[5];
    const float* bk  = (const float*)d_in[6];
    const float* Wv  = (const float*)d_in[7];
    const float* bv  = (const float*)d_in[8];
    const float* Wg1 = (const float*)d_in[9];
    const float* bg1 = (const float*)d_in[10];
    const float* Wg2 = (const float*)d_in[11];
    const float* bg2 = (const float*)d_in[12];
    const float* tsc = (const float*)d_in[13];

    const int S = 2048, D = 768, Bc = 8;
    const int MS = Bc * S;                     // 16384
    const long long SD = (long long)S * D;     // 1,572,864
    const long long SS = (long long)S * S;     // 4,194,304
    const long long MSD = (long long)MS * D;   // 12,582,912

    // ws layout (bytes):
    //   q/att @0 (24MiB) | k/rinv/h @24MiB | vT @48MiB | P @72MiB (64MiB) | Wb @136MiB
    //   X (qkv bf16, 72MiB) @48MiB overlays vT+P (dead before vT/P written)
    //   rinv (64KB) overlays k (k dead after scores); psums (2MB f32) parked in d_out
    char* ws = (char*)d_ws;
    ushort_t* q    = (ushort_t*)(ws);
    ushort_t* att  = q;                        // PV overwrites q after scores consumed it
    ushort_t* k    = (ushort_t*)(ws + 25165824ll);
    float*    rinv = (float*)(ws + 25165824ll);
    ushort_t* h    = k;
    ushort_t* vT   = (ushort_t*)(ws + 50331648ll);
    ushort_t* X    = (ushort_t*)(ws + 50331648ll);  // 3 x 24MiB
    ushort_t* P    = (ushort_t*)(ws + 75497472ll);
    ushort_t* Wb   = (ushort_t*)(ws + 142606336ll);
    ushort_t* v    = (ushort_t*)d_out;         // bf16 v in front of d_out until transpose
    float*  psums  = (float*)d_out;            // 2MB, alive only between scores and finalize

    const int WQ = 0, WG1 = 1769472, WG2 = 2359296;
    const int BQ = 2949120, BG1 = 2951424, BG2 = 2952192, TSO = 2952960;

    const dim3 blk(256);
    const float scale = 0.03608439182435161f; // 1/sqrt(768)

    // 0. convert params + inputs to bf16
    convert_params<<<dim3((NTOT / 8 + 255) / 256), blk, 0, stream>>>(
        Wq, Wk, Wv, Wg1, Wg2, bq, bk, bv, bg1, bg2, tsc, Wb);
    convert_inputs<<<dim3(18432), blk, 0, stream>>>(query, key_, value, X);
    // 1. fused QKV projections: bz=0->q, 1->k, 2->v (d_out)
    gemm_bt<1, 0, 1><<<dim3(D / 128, MS / 128, 3), blk, 0, stream>>>(
        X, Wb + WQ, q, v, Wb + BQ, nullptr, nullptr, nullptr, nullptr,
        MS, D, D, 1.f, MSD, (long long)WSEG, MSD);
    // 2. vT = transpose(v) per batch; v and X dead afterwards
    transpose2d<<<dim3(D / 64, S / 64, Bc), blk, 0, stream>>>(v, vT, S, D);
    // 3. P = exp(q @ k^T * scale), + per-block row partials -> psums (d_out)
    gemm_bt<5, 0, 0><<<dim3(S / 128, S / 128, Bc), blk, 0, stream>>>(
        q, k, P, nullptr, nullptr, nullptr, nullptr, nullptr, psums,
        S, S, D, scale, SD, SD, SS);
    // 4. rinv[row] = 1/rowsum (16 partials per row; 16384 rows)
    finalize_rinv<<<dim3(MS / 256), blk, 0, stream>>>(psums, rinv, S / 128);
    // 5. att = (P @ vT^T) * rinv   (batched; att overlays q)
    gemm_bt<7, 0, 0><<<dim3(D / 128, S / 128, Bc), blk, 0, stream>>>(
        P, vT, att, nullptr, nullptr, nullptr, nullptr, rinv, nullptr,
        S, D, S, 1.f, SS, SD, SD);
    // 6. h = relu(att @ Wg1^T + bg1)  (h overlays k/rinv -- rinv consumed)
    gemm_bt<3, 0, 0><<<dim3(D / 128, MS / 128, 1), blk, 0, stream>>>(
        att, Wb + WG1, h, nullptr, Wb + BG1, nullptr, nullptr, nullptr, nullptr,
        MS, D, D, 1.f, 0, 0, 0);
    // 7. out = sigmoid(sigmoid(h @ Wg2^T + bg2)) * att * ts  (f32 -> d_out)
    gemm_bt<4, 1, 0><<<dim3(D / 128, MS / 128, 1), blk, 0, stream>>>(
        h, Wb + WG2, d_out, nullptr, Wb + BG2, att, Wb + TSO, nullptr, nullptr,
        MS, D, D, 1.f, 0, 0, 0);
}

// Round 13
// 326.118 us; speedup vs baseline: 1.0318x; 1.0152x over previous
//
#include <hip/hip_runtime.h>

typedef unsigned short ushort_t;
typedef __bf16 bf16x8 __attribute__((ext_vector_type(8)));
typedef float f32x4 __attribute__((ext_vector_type(4)));
typedef short short8 __attribute__((ext_vector_type(8)));

#define SBAR()   asm volatile("s_barrier" ::: "memory")
#define WAITV0() asm volatile("s_waitcnt vmcnt(0)" ::: "memory")
#define WAITV4() asm volatile("s_waitcnt vmcnt(4)" ::: "memory")
#define WAITV8() asm volatile("s_waitcnt vmcnt(8)" ::: "memory")

__device__ __forceinline__ float bf2f(unsigned short u) {
    union { unsigned int i; float f; } v; v.i = ((unsigned int)u) << 16; return v.f;
}
__device__ __forceinline__ unsigned short f2bf(float f) {
    union { float f; unsigned int i; } v; v.f = f;
    unsigned int r = v.i + 0x7fffu + ((v.i >> 16) & 1u);
    return (unsigned short)(r >> 16);
}
__device__ __forceinline__ float sigm(float x) { return 1.0f / (1.0f + __expf(-x)); }

__device__ __forceinline__ void async_copy16(const ushort_t* src, ushort_t* dst_lds) {
    __builtin_amdgcn_global_load_lds(
        (const __attribute__((address_space(1))) void*)src,
        (__attribute__((address_space(3))) void*)dst_lds,
        16, 0, 0);
}

// ---- merged f32->bf16 conversion: inputs (q,k,v -> X) + params (5W+5b+ts -> Wb) ----
#define WSEG 589824           // 768*768
#define NWALL 2949120         // 5*WSEG
#define NTOT 2953728          // + 6*768
#define PERT 12582912ll       // 16384*768
#define INBLK 18432           // 3*PERT/8/256
__global__ __launch_bounds__(256)
void convert_all(const float* __restrict__ qi, const float* __restrict__ ki,
                 const float* __restrict__ vi,
                 const float* __restrict__ Wq, const float* __restrict__ Wk,
                 const float* __restrict__ Wv, const float* __restrict__ Wg1,
                 const float* __restrict__ Wg2, const float* __restrict__ bq,
                 const float* __restrict__ bk, const float* __restrict__ bv,
                 const float* __restrict__ bg1, const float* __restrict__ bg2,
                 const float* __restrict__ ts,
                 ushort_t* __restrict__ X, ushort_t* __restrict__ Wb)
{
    if (blockIdx.x < INBLK) {
        long long i = ((long long)blockIdx.x * 256 + threadIdx.x) * 8;
        const float* src; long long off;
        if (i < PERT)          { src = qi; off = i; }
        else if (i < 2 * PERT) { src = ki; off = i - PERT; }
        else                   { src = vi; off = i - 2 * PERT; }
        float4 a = *(const float4*)(src + off);
        float4 b = *(const float4*)(src + off + 4);
        short8 o;
        o[0] = (short)f2bf(a.x); o[1] = (short)f2bf(a.y); o[2] = (short)f2bf(a.z); o[3] = (short)f2bf(a.w);
        o[4] = (short)f2bf(b.x); o[5] = (short)f2bf(b.y); o[6] = (short)f2bf(b.z); o[7] = (short)f2bf(b.w);
        *(short8*)(X + i) = o;
    } else {
        int e = ((blockIdx.x - INBLK) * 256 + threadIdx.x) * 8;
        if (e >= NTOT) return;
        const float* src; int off;
        if (e < NWALL) {
            int wi = e / WSEG; off = e - wi * WSEG;
            src = (wi == 0) ? Wq : (wi == 1) ? Wk : (wi == 2) ? Wv : (wi == 3) ? Wg1 : Wg2;
        } else {
            int j = e - NWALL; int bi = j / 768; off = j - bi * 768;
            src = (bi == 0) ? bq : (bi == 1) ? bk : (bi == 2) ? bv : (bi == 3) ? bg1 : (bi == 4) ? bg2 : ts;
        }
        float4 a = *(const float4*)(src + off);
        float4 b = *(const float4*)(src + off + 4);
        short8 o;
        o[0] = (short)f2bf(a.x); o[1] = (short)f2bf(a.y); o[2] = (short)f2bf(a.z); o[3] = (short)f2bf(a.w);
        o[4] = (short)f2bf(b.x); o[5] = (short)f2bf(b.y); o[6] = (short)f2bf(b.z); o[7] = (short)f2bf(b.w);
        *(short8*)(Wb + e) = o;
    }
}

// C[M,N] = A[M,K] @ B[N,K]^T (+ epilogue), optionally batched (M = rows per batch).
// All-bf16 operands via global_load_lds; 3-buffer 2-deep counted-vmcnt pipeline, raw s_barrier.
// CF32: f32 store. QKV: gridDim.z=3; bz selects dest {Cv+bz*batchC | Cv2 for bz==2}, bias+bz*768.
// EPI: 0=plain, 1=+bias, 3=+bias+relu, 4=gate sigmoid(sigmoid(x+bias))*aux*ts,
//      5=exp(x*scale) + per-block row partial sums -> psum_out[bz*M+row][gridDim.x],
//      7=multiply by 1/rowsum computed in-prologue from psum_out (16 partials/row)
// Requires gridDim.x*gridDim.y*gridDim.z % 8 == 0, K%32==0, K>=64.
template<int EPI, int CF32, int QKV>
__global__ __launch_bounds__(256, 2)
void gemm_bt(const ushort_t* __restrict__ A, const ushort_t* __restrict__ B,
             void* __restrict__ Cv, void* __restrict__ Cv2,
             const ushort_t* __restrict__ bias,
             const ushort_t* __restrict__ aux, const ushort_t* __restrict__ ts,
             float* __restrict__ psum_out,
             int M, int N, int K, float scale,
             long long batchA, long long batchB, long long batchC)
{
    __shared__ __align__(16) ushort_t As[3][128 * 32];
    __shared__ __align__(16) ushort_t Bs[3][128 * 32];
    __shared__ float rsmx[256];
    const int tid  = threadIdx.x;
    const int lane = tid & 63;
    const int wave = tid >> 6;
    const int wr = wave >> 1, wc = wave & 1;

    // XCD-aware bijective swizzle over the full flat grid (nwg % 8 == 0)
    const int gx = gridDim.x, gy = gridDim.y;
    const int nwg = gx * gy * gridDim.z;
    int fid = (blockIdx.z * gy + blockIdx.y) * gx + blockIdx.x;
    fid = (fid & 7) * (nwg >> 3) + (fid >> 3);
    const int bz  = fid / (gx * gy);
    const int rem = fid - bz * (gx * gy);
    const int by  = rem / gx;
    const int bx  = rem - by * gx;
    const int row0 = by * 128;
    const int col0 = bx * 128;

    // EPI=7: per-block rinv for its 128 rows from psums (16 = scores gridDim.x = S/128).
    // Bit-identical to the former finalize_rinv (same order f32 adds).
    if (EPI == 7) {
        if (tid < 128) {
            const float* pp = psum_out + ((size_t)bz * M + row0 + tid) * 16;
            float s = 0.f;
            #pragma unroll
            for (int i = 0; i < 16; ++i) s += pp[i];
            rsmx[tid] = 1.0f / s;
        }
        __syncthreads();
    }

    f32x4 acc[4][4] = {};

    // staging: 256 threads x 16B = 64 rows of 32 bf16 per inst
    const int srow = tid >> 2;
    const int scol = (tid & 3) * 8;
    const ushort_t* ga0 = A + batchA * bz + (size_t)(row0 + srow) * K + scol;
    const ushort_t* gb0 = B + batchB * bz + (size_t)(col0 + srow) * K + scol;

    const int kop  = (lane >> 4) * 8;
    const int arow = wr * 64 + (lane & 15);
    const int brow = wc * 64 + (lane & 15);

    const int NT = K >> 5;

#define STAGE4(T, BUF) do { const int kk_ = (T) * 32; \
    async_copy16(ga0 + kk_,                  &As[BUF][0] + tid * 8); \
    async_copy16(ga0 + (size_t)64 * K + kk_, &As[BUF][0] + 2048 + tid * 8); \
    async_copy16(gb0 + kk_,                  &Bs[BUF][0] + tid * 8); \
    async_copy16(gb0 + (size_t)64 * K + kk_, &Bs[BUF][0] + 2048 + tid * 8); \
} while (0)

    STAGE4(0, 0);
    STAGE4(1, 1);

    int cur = 0;
    for (int t = 0; t < NT; ++t) {
        if (t + 2 < NT) {
            int nb = cur + 2; if (nb >= 3) nb -= 3;
            STAGE4(t + 2, nb);
            WAITV8();   // tile t landed; tiles t+1, t+2 (8 loads) in flight
        } else if (t + 1 < NT) {
            WAITV4();   // tile t landed; tile t+1 in flight
        } else {
            WAITV0();
        }
        SBAR();
        const ushort_t* Ac = &As[0][0] + cur * 4096;
        const ushort_t* Bc = &Bs[0][0] + cur * 4096;
        bf16x8 af[4], bfr[4];
        #pragma unroll
        for (int m = 0; m < 4; ++m)
            af[m] = *(const bf16x8*)(Ac + (arow + m * 16) * 32 + kop);
        #pragma unroll
        for (int n = 0; n < 4; ++n)
            bfr[n] = *(const bf16x8*)(Bc + (brow + n * 16) * 32 + kop);
        #pragma unroll
        for (int m = 0; m < 4; ++m)
            #pragma unroll
            for (int n = 0; n < 4; ++n)
                acc[m][n] = __builtin_amdgcn_mfma_f32_16x16x32_bf16(af[m], bfr[n], acc[m][n], 0, 0, 0);
        SBAR();
        ++cur; if (cur >= 3) cur = 0;
    }
#undef STAGE4

    // epilogue: C/D layout col=lane&15, row=(lane>>4)*4+reg
    const int r0 = row0 + wr * 64 + (lane >> 4) * 4;
    const int c0 = col0 + wc * 64 + (lane & 15);

    float rv[4][4];
    if (EPI == 7) {
        #pragma unroll
        for (int m = 0; m < 4; ++m)
            #pragma unroll
            for (int r = 0; r < 4; ++r)
                rv[m][r] = rsmx[wr * 64 + m * 16 + (lane >> 4) * 4 + r];
    }
    float rsum[4][4] = {};

    ushort_t* Cb = (QKV && bz == 2) ? (ushort_t*)Cv2 : (ushort_t*)Cv + batchC * bz;
    float* Cf = (float*)Cv;
    #pragma unroll
    for (int m = 0; m < 4; ++m) {
        #pragma unroll
        for (int n = 0; n < 4; ++n) {
            const int col = c0 + n * 16;
            #pragma unroll
            for (int r = 0; r < 4; ++r) {
                const int row = r0 + m * 16 + r;
                float val = acc[m][n][r];
                if (EPI == 1) {
                    val += bf2f(bias[(QKV ? bz * 768 : 0) + col]);
                } else if (EPI == 3) {
                    val += bf2f(bias[col]);
                    val = fmaxf(val, 0.0f);
                } else if (EPI == 4) {
                    val += bf2f(bias[col]);
                    float g  = sigm(val);
                    float gg = sigm(g);
                    val = gg * bf2f(aux[(size_t)row * N + col]) * bf2f(ts[col]);
                } else if (EPI == 5) {
                    val = __expf(val * scale);
                    rsum[m][r] += val;
                } else if (EPI == 7) {
                    val *= rv[m][r];
                }
                if (CF32) Cf[(size_t)row * N + col] = val;
                else      Cb[(size_t)row * N + col] = f2bf(val);
            }
        }
    }

    if (EPI == 5) {
        // reduce over the 16 lanes holding the wave's 16-col groups (lane bits 0..3)
        #pragma unroll
        for (int m = 0; m < 4; ++m)
            #pragma unroll
            for (int r = 0; r < 4; ++r) {
                float s = rsum[m][r];
                s += __shfl_xor(s, 1);
                s += __shfl_xor(s, 2);
                s += __shfl_xor(s, 4);
                s += __shfl_xor(s, 8);
                rsum[m][r] = s;
            }
        if ((lane & 15) == 0) {
            const int quad = lane >> 4;
            #pragma unroll
            for (int m = 0; m < 4; ++m)
                #pragma unroll
                for (int r = 0; r < 4; ++r)
                    rsmx[(wr * 64 + m * 16 + quad * 4 + r) * 2 + wc] = rsum[m][r];
        }
        __syncthreads();
        if (tid < 128) {
            float s = rsmx[tid * 2] + rsmx[tid * 2 + 1];
            psum_out[((size_t)bz * M + row0 + tid) * gx + bx] = s;
        }
    }
}

// VT[z][c][r] = V[z][r][c];  64x64 tiles, short8 both directions.
// grid (C/64, R/64, Z), block 256. R, C per-batch dims.
__global__ __launch_bounds__(256)
void transpose2d(const ushort_t* __restrict__ V, ushort_t* __restrict__ VT, int R, int Ccols)
{
    __shared__ ushort_t t[64][72];
    const size_t zoff = (size_t)blockIdx.z * R * Ccols;
    const int r0 = blockIdx.y * 64;
    const int c0 = blockIdx.x * 64;
    const int tid = threadIdx.x;

    const int lr = tid >> 2;
    const int lc = (tid & 3) * 16;
    const ushort_t* src = V + zoff + (size_t)(r0 + lr) * Ccols + c0 + lc;
    short8 a = *(const short8*)(src);
    short8 b = *(const short8*)(src + 8);
    *(short8*)(&t[lr][lc])     = a;
    *(short8*)(&t[lr][lc + 8]) = b;
    __syncthreads();

    const int oc = tid >> 2;
    const int orr = (tid & 3) * 16;
    short8 o1, o2;
    #pragma unroll
    for (int j = 0; j < 8; ++j) {
        o1[j] = (short)t[orr + j][oc];
        o2[j] = (short)t[orr + 8 + j][oc];
    }
    ushort_t* dst = VT + zoff + (size_t)(c0 + oc) * R + r0 + orr;
    *(short8*)(dst)     = o1;
    *(short8*)(dst + 8) = o2;
}

extern "C" void kernel_launch(void* const* d_in, const int* in_sizes, int n_in,
                              void* d_out, int out_size, void* d_ws, size_t ws_size,
                              hipStream_t stream)
{
    (void)in_sizes; (void)n_in; (void)out_size; (void)ws_size;
    const float* query = (const float*)d_in[0];
    const float* key_  = (const float*)d_in[1];
    const float* value = (const float*)d_in[2];
    const float* Wq  = (const float*)d_in[3];
    const float* bq  = (const float*)d_in[4];
    const float* Wk  = (const float*)d_in[5];
    const float* bk  = (const float*)d_in[6];
    const float* Wv  = (const float*)d_in[7];
    const float* bv  = (const float*)d_in[8];
    const float* Wg1 = (const float*)d_in[9];
    const float* bg1 = (const float*)d_in[10];
    const float* Wg2 = (const float*)d_in[11];
    const float* bg2 = (const float*)d_in[12];
    const float* tsc = (const float*)d_in[13];

    const int S = 2048, D = 768, Bc = 8;
    const int MS = Bc * S;                     // 16384
    const long long SD = (long long)S * D;     // 1,572,864
    const long long SS = (long long)S * S;     // 4,194,304
    const long long MSD = (long long)MS * D;   // 12,582,912

    // ws layout (bytes):
    //   q/att @0 (24MiB) | k/h @24MiB | vT @48MiB | P @72MiB (64MiB) | Wb @136MiB
    //   X (qkv bf16, 72MiB) @48MiB overlays vT+P (dead before vT/P written)
    //   psums (2MB f32) parked in d_out (v dead after transpose; d_out rewritten by final GEMM)
    char* ws = (char*)d_ws;
    ushort_t* q    = (ushort_t*)(ws);
    ushort_t* att  = q;                        // PV overwrites q after scores consumed it
    ushort_t* k    = (ushort_t*)(ws + 25165824ll);
    ushort_t* h    = k;                        // k dead after scores
    ushort_t* vT   = (ushort_t*)(ws + 50331648ll);
    ushort_t* X    = (ushort_t*)(ws + 50331648ll);  // 3 x 24MiB
    ushort_t* P    = (ushort_t*)(ws + 75497472ll);
    ushort_t* Wb   = (ushort_t*)(ws + 142606336ll);
    ushort_t* v    = (ushort_t*)d_out;         // bf16 v in front of d_out until transpose
    float*  psums  = (float*)d_out;            // 2MB, alive only between scores and PV

    const int WQ = 0, WG1 = 1769472, WG2 = 2359296;
    const int BQ = 2949120, BG1 = 2951424, BG2 = 2952192, TSO = 2952960;

    const dim3 blk(256);
    const float scale = 0.03608439182435161f; // 1/sqrt(768)

    // 0. convert inputs + params to bf16 (single launch)
    convert_all<<<dim3(INBLK + (NTOT / 8 + 255) / 256), blk, 0, stream>>>(
        query, key_, value, Wq, Wk, Wv, Wg1, Wg2, bq, bk, bv, bg1, bg2, tsc, X, Wb);
    // 1. fused QKV projections: bz=0->q, 1->k, 2->v (d_out)
    gemm_bt<1, 0, 1><<<dim3(D / 128, MS / 128, 3), blk, 0, stream>>>(
        X, Wb + WQ, q, v, Wb + BQ, nullptr, nullptr, nullptr,
        MS, D, D, 1.f, MSD, (long long)WSEG, MSD);
    // 2. vT = transpose(v) per batch; v and X dead afterwards
    transpose2d<<<dim3(D / 64, S / 64, Bc), blk, 0, stream>>>(v, vT, S, D);
    // 3. P = exp(q @ k^T * scale), + per-block row partials -> psums (d_out)
    gemm_bt<5, 0, 0><<<dim3(S / 128, S / 128, Bc), blk, 0, stream>>>(
        q, k, P, nullptr, nullptr, nullptr, nullptr, psums,
        S, S, D, scale, SD, SD, SS);
    // 4. att = (P @ vT^T) / rowsum   (rinv computed in-prologue from psums; att overlays q)
    gemm_bt<7, 0, 0><<<dim3(D / 128, S / 128, Bc), blk, 0, stream>>>(
        P, vT, att, nullptr, nullptr, nullptr, nullptr, psums,
        S, D, S, 1.f, SS, SD, SD);
    // 5. h = relu(att @ Wg1^T + bg1)  (h overlays k)
    gemm_bt<3, 0, 0><<<dim3(D / 128, MS / 128, 1), blk, 0, stream>>>(
        att, Wb + WG1, h, nullptr, Wb + BG1, nullptr, nullptr, nullptr,
        MS, D, D, 1.f, 0, 0, 0);
    // 6. out = sigmoid(sigmoid(h @ Wg2^T + bg2)) * att * ts  (f32 -> d_out, overwrites psums)
    gemm_bt<4, 1, 0><<<dim3(D / 128, MS / 128, 1), blk, 0, stream>>>(
        h, Wb + WG2, d_out, nullptr, Wb + BG2, att, Wb + TSO, nullptr,
        MS, D, D, 1.f, 0, 0, 0);
}

// Round 14
// 320.686 us; speedup vs baseline: 1.0493x; 1.0169x over previous
//
#include <hip/hip_runtime.h>

typedef unsigned short ushort_t;
typedef __bf16 bf16x8 __attribute__((ext_vector_type(8)));
typedef float f32x4 __attribute__((ext_vector_type(4)));
typedef short short8 __attribute__((ext_vector_type(8)));
typedef short short4v __attribute__((ext_vector_type(4)));

#define SBAR()   asm volatile("s_barrier" ::: "memory")
#define WAITV0() asm volatile("s_waitcnt vmcnt(0)" ::: "memory")
#define WAITV4() asm volatile("s_waitcnt vmcnt(4)" ::: "memory")
#define WAITV8() asm volatile("s_waitcnt vmcnt(8)" ::: "memory")

__device__ __forceinline__ float bf2f(unsigned short u) {
    union { unsigned int i; float f; } v; v.i = ((unsigned int)u) << 16; return v.f;
}
__device__ __forceinline__ unsigned short f2bf(float f) {
    union { float f; unsigned int i; } v; v.f = f;
    unsigned int r = v.i + 0x7fffu + ((v.i >> 16) & 1u);
    return (unsigned short)(r >> 16);
}
__device__ __forceinline__ float sigm(float x) { return 1.0f / (1.0f + __expf(-x)); }

__device__ __forceinline__ void async_copy16(const ushort_t* src, ushort_t* dst_lds) {
    __builtin_amdgcn_global_load_lds(
        (const __attribute__((address_space(1))) void*)src,
        (__attribute__((address_space(3))) void*)dst_lds,
        16, 0, 0);
}

// ---- merged f32->bf16 conversion: inputs (q,k,v -> X) + params (5W+5b+ts -> Wb) ----
#define WSEG 589824           // 768*768
#define NWALL 2949120         // 5*WSEG
#define NTOT 2953728          // + 6*768
#define PERT 12582912ll       // 16384*768
#define INBLK 18432           // 3*PERT/8/256
__global__ __launch_bounds__(256)
void convert_all(const float* __restrict__ qi, const float* __restrict__ ki,
                 const float* __restrict__ vi,
                 const float* __restrict__ Wq, const float* __restrict__ Wk,
                 const float* __restrict__ Wv, const float* __restrict__ Wg1,
                 const float* __restrict__ Wg2, const float* __restrict__ bq,
                 const float* __restrict__ bk, const float* __restrict__ bv,
                 const float* __restrict__ bg1, const float* __restrict__ bg2,
                 const float* __restrict__ ts,
                 ushort_t* __restrict__ X, ushort_t* __restrict__ Wb)
{
    if (blockIdx.x < INBLK) {
        long long i = ((long long)blockIdx.x * 256 + threadIdx.x) * 8;
        const float* src; long long off;
        if (i < PERT)          { src = qi; off = i; }
        else if (i < 2 * PERT) { src = ki; off = i - PERT; }
        else                   { src = vi; off = i - 2 * PERT; }
        float4 a = *(const float4*)(src + off);
        float4 b = *(const float4*)(src + off + 4);
        short8 o;
        o[0] = (short)f2bf(a.x); o[1] = (short)f2bf(a.y); o[2] = (short)f2bf(a.z); o[3] = (short)f2bf(a.w);
        o[4] = (short)f2bf(b.x); o[5] = (short)f2bf(b.y); o[6] = (short)f2bf(b.z); o[7] = (short)f2bf(b.w);
        *(short8*)(X + i) = o;
    } else {
        int e = ((blockIdx.x - INBLK) * 256 + threadIdx.x) * 8;
        if (e >= NTOT) return;
        const float* src; int off;
        if (e < NWALL) {
            int wi = e / WSEG; off = e - wi * WSEG;
            src = (wi == 0) ? Wq : (wi == 1) ? Wk : (wi == 2) ? Wv : (wi == 3) ? Wg1 : Wg2;
        } else {
            int j = e - NWALL; int bi = j / 768; off = j - bi * 768;
            src = (bi == 0) ? bq : (bi == 1) ? bk : (bi == 2) ? bv : (bi == 3) ? bg1 : (bi == 4) ? bg2 : ts;
        }
        float4 a = *(const float4*)(src + off);
        float4 b = *(const float4*)(src + off + 4);
        short8 o;
        o[0] = (short)f2bf(a.x); o[1] = (short)f2bf(a.y); o[2] = (short)f2bf(a.z); o[3] = (short)f2bf(a.w);
        o[4] = (short)f2bf(b.x); o[5] = (short)f2bf(b.y); o[6] = (short)f2bf(b.z); o[7] = (short)f2bf(b.w);
        *(short8*)(Wb + e) = o;
    }
}

// C[M,N] = A[M,K] @ B[N,K]^T (+ epilogue), optionally batched (M = rows per batch).
// All-bf16 operands via global_load_lds; 3-buffer 2-deep counted-vmcnt pipeline, raw s_barrier.
// CF32: f32 store. QKV: gridDim.z=3; bz=0/1 -> Cv+bz*batchC (row-major), bz=2 -> Cv2 in
// TRANSPOSED per-batch layout vT[z][col][row] (z=row>>11); bias+bz*768.
// EPI: 0=plain, 1=+bias, 3=+bias+relu, 4=gate sigmoid(sigmoid(x+bias))*aux*ts,
//      5=exp(x*scale) + per-block row partial sums -> psum_out[bz*M+row][gridDim.x],
//      7=multiply by 1/rowsum computed in-prologue from psum_out (16 partials/row)
// Requires gridDim.x*gridDim.y*gridDim.z % 8 == 0, K%32==0, K>=64.
template<int EPI, int CF32, int QKV>
__global__ __launch_bounds__(256, 2)
void gemm_bt(const ushort_t* __restrict__ A, const ushort_t* __restrict__ B,
             void* __restrict__ Cv, void* __restrict__ Cv2,
             const ushort_t* __restrict__ bias,
             const ushort_t* __restrict__ aux, const ushort_t* __restrict__ ts,
             float* __restrict__ psum_out,
             int M, int N, int K, float scale,
             long long batchA, long long batchB, long long batchC)
{
    __shared__ __align__(16) ushort_t As[3][128 * 32];
    __shared__ __align__(16) ushort_t Bs[3][128 * 32];
    __shared__ float rsmx[256];
    const int tid  = threadIdx.x;
    const int lane = tid & 63;
    const int wave = tid >> 6;
    const int wr = wave >> 1, wc = wave & 1;

    // XCD-aware bijective swizzle over the full flat grid (nwg % 8 == 0)
    const int gx = gridDim.x, gy = gridDim.y;
    const int nwg = gx * gy * gridDim.z;
    int fid = (blockIdx.z * gy + blockIdx.y) * gx + blockIdx.x;
    fid = (fid & 7) * (nwg >> 3) + (fid >> 3);
    const int bz  = fid / (gx * gy);
    const int rem = fid - bz * (gx * gy);
    const int by  = rem / gx;
    const int bx  = rem - by * gx;
    const int row0 = by * 128;
    const int col0 = bx * 128;

    // EPI=7: per-block rinv for its 128 rows from psums (16 = scores gridDim.x = S/128).
    if (EPI == 7) {
        if (tid < 128) {
            const float* pp = psum_out + ((size_t)bz * M + row0 + tid) * 16;
            float s = 0.f;
            #pragma unroll
            for (int i = 0; i < 16; ++i) s += pp[i];
            rsmx[tid] = 1.0f / s;
        }
        __syncthreads();
    }

    f32x4 acc[4][4] = {};

    // staging: 256 threads x 16B = 64 rows of 32 bf16 per inst
    const int srow = tid >> 2;
    const int scol = (tid & 3) * 8;
    const ushort_t* ga0 = A + batchA * bz + (size_t)(row0 + srow) * K + scol;
    const ushort_t* gb0 = B + batchB * bz + (size_t)(col0 + srow) * K + scol;

    const int kop  = (lane >> 4) * 8;
    const int arow = wr * 64 + (lane & 15);
    const int brow = wc * 64 + (lane & 15);

    const int NT = K >> 5;

#define STAGE4(T, BUF) do { const int kk_ = (T) * 32; \
    async_copy16(ga0 + kk_,                  &As[BUF][0] + tid * 8); \
    async_copy16(ga0 + (size_t)64 * K + kk_, &As[BUF][0] + 2048 + tid * 8); \
    async_copy16(gb0 + kk_,                  &Bs[BUF][0] + tid * 8); \
    async_copy16(gb0 + (size_t)64 * K + kk_, &Bs[BUF][0] + 2048 + tid * 8); \
} while (0)

    STAGE4(0, 0);
    STAGE4(1, 1);

    int cur = 0;
    for (int t = 0; t < NT; ++t) {
        if (t + 2 < NT) {
            int nb = cur + 2; if (nb >= 3) nb -= 3;
            STAGE4(t + 2, nb);
            WAITV8();   // tile t landed; tiles t+1, t+2 (8 loads) in flight
        } else if (t + 1 < NT) {
            WAITV4();   // tile t landed; tile t+1 in flight
        } else {
            WAITV0();
        }
        SBAR();
        const ushort_t* Ac = &As[0][0] + cur * 4096;
        const ushort_t* Bc = &Bs[0][0] + cur * 4096;
        bf16x8 af[4], bfr[4];
        #pragma unroll
        for (int m = 0; m < 4; ++m)
            af[m] = *(const bf16x8*)(Ac + (arow + m * 16) * 32 + kop);
        #pragma unroll
        for (int n = 0; n < 4; ++n)
            bfr[n] = *(const bf16x8*)(Bc + (brow + n * 16) * 32 + kop);
        #pragma unroll
        for (int m = 0; m < 4; ++m)
            #pragma unroll
            for (int n = 0; n < 4; ++n)
                acc[m][n] = __builtin_amdgcn_mfma_f32_16x16x32_bf16(af[m], bfr[n], acc[m][n], 0, 0, 0);
        SBAR();
        ++cur; if (cur >= 3) cur = 0;
    }
#undef STAGE4

    // epilogue: C/D layout col=lane&15, row=(lane>>4)*4+reg
    const int r0 = row0 + wr * 64 + (lane >> 4) * 4;
    const int c0 = col0 + wc * 64 + (lane & 15);

    float rv[4][4];
    if (EPI == 7) {
        #pragma unroll
        for (int m = 0; m < 4; ++m)
            #pragma unroll
            for (int r = 0; r < 4; ++r)
                rv[m][r] = rsmx[wr * 64 + m * 16 + (lane >> 4) * 4 + r];
    }
    float rsum[4][4] = {};

    if (QKV && bz == 2) {
        // v written TRANSPOSED: vT[z][col][row], z = row>>11, r = row&2047.
        // 4 consecutive r per (m,n) -> one 8B short4 store.
        ushort_t* vT = (ushort_t*)Cv2 + ((size_t)(row0 >> 11)) * 1572864ll;
        #pragma unroll
        for (int m = 0; m < 4; ++m) {
            const int rr = (r0 + m * 16) & 2047;
            #pragma unroll
            for (int n = 0; n < 4; ++n) {
                const int col = c0 + n * 16;
                const float bv_ = bf2f(bias[2 * 768 + col]);
                short4v o;
                #pragma unroll
                for (int r = 0; r < 4; ++r)
                    o[r] = (short)f2bf(acc[m][n][r] + bv_);
                *(short4v*)(vT + (size_t)col * 2048 + rr) = o;
            }
        }
        return;
    }

    ushort_t* Cb = (ushort_t*)Cv + batchC * bz;
    float* Cf = (float*)Cv;
    #pragma unroll
    for (int m = 0; m < 4; ++m) {
        #pragma unroll
        for (int n = 0; n < 4; ++n) {
            const int col = c0 + n * 16;
            #pragma unroll
            for (int r = 0; r < 4; ++r) {
                const int row = r0 + m * 16 + r;
                float val = acc[m][n][r];
                if (EPI == 1) {
                    val += bf2f(bias[(QKV ? bz * 768 : 0) + col]);
                } else if (EPI == 3) {
                    val += bf2f(bias[col]);
                    val = fmaxf(val, 0.0f);
                } else if (EPI == 4) {
                    val += bf2f(bias[col]);
                    float g  = sigm(val);
                    float gg = sigm(g);
                    val = gg * bf2f(aux[(size_t)row * N + col]) * bf2f(ts[col]);
                } else if (EPI == 5) {
                    val = __expf(val * scale);
                    rsum[m][r] += val;
                } else if (EPI == 7) {
                    val *= rv[m][r];
                }
                if (CF32) Cf[(size_t)row * N + col] = val;
                else      Cb[(size_t)row * N + col] = f2bf(val);
            }
        }
    }

    if (EPI == 5) {
        // reduce over the 16 lanes holding the wave's 16-col groups (lane bits 0..3)
        #pragma unroll
        for (int m = 0; m < 4; ++m)
            #pragma unroll
            for (int r = 0; r < 4; ++r) {
                float s = rsum[m][r];
                s += __shfl_xor(s, 1);
                s += __shfl_xor(s, 2);
                s += __shfl_xor(s, 4);
                s += __shfl_xor(s, 8);
                rsum[m][r] = s;
            }
        if ((lane & 15) == 0) {
            const int quad = lane >> 4;
            #pragma unroll
            for (int m = 0; m < 4; ++m)
                #pragma unroll
                for (int r = 0; r < 4; ++r)
                    rsmx[(wr * 64 + m * 16 + quad * 4 + r) * 2 + wc] = rsum[m][r];
        }
        __syncthreads();
        if (tid < 128) {
            float s = rsmx[tid * 2] + rsmx[tid * 2 + 1];
            psum_out[((size_t)bz * M + row0 + tid) * gx + bx] = s;
        }
    }
}

extern "C" void kernel_launch(void* const* d_in, const int* in_sizes, int n_in,
                              void* d_out, int out_size, void* d_ws, size_t ws_size,
                              hipStream_t stream)
{
    (void)in_sizes; (void)n_in; (void)out_size; (void)ws_size;
    const float* query = (const float*)d_in[0];
    const float* key_  = (const float*)d_in[1];
    const float* value = (const float*)d_in[2];
    const float* Wq  = (const float*)d_in[3];
    const float* bq  = (const float*)d_in[4];
    const float* Wk  = (const float*)d_in[5];
    const float* bk  = (const float*)d_in[6];
    const float* Wv  = (const float*)d_in[7];
    const float* bv  = (const float*)d_in[8];
    const float* Wg1 = (const float*)d_in[9];
    const float* bg1 = (const float*)d_in[10];
    const float* Wg2 = (const float*)d_in[11];
    const float* bg2 = (const float*)d_in[12];
    const float* tsc = (const float*)d_in[13];

    const int S = 2048, D = 768, Bc = 8;
    const int MS = Bc * S;                     // 16384
    const long long SD = (long long)S * D;     // 1,572,864
    const long long SS = (long long)S * S;     // 4,194,304
    const long long MSD = (long long)MS * D;   // 12,582,912

    // ws layout (bytes):
    //   q/att @0 (24MiB) | k/h @24MiB | X @48MiB (72MiB) | P @72MiB (64MiB, overlays X tail
    //   after QKV) | Wb @136MiB
    // d_out: vT (24MiB, written transposed by QKV) | psums @24MiB (2MB) -> both dead before
    //   the final f32 output overwrites d_out.
    char* ws = (char*)d_ws;
    ushort_t* q    = (ushort_t*)(ws);
    ushort_t* att  = q;                        // PV overwrites q after scores consumed it
    ushort_t* k    = (ushort_t*)(ws + 25165824ll);
    ushort_t* h    = k;                        // k dead after scores
    ushort_t* X    = (ushort_t*)(ws + 50331648ll);  // 3 x 24MiB
    ushort_t* P    = (ushort_t*)(ws + 75497472ll);  // overlays X[1..2] after QKV
    ushort_t* Wb   = (ushort_t*)(ws + 142606336ll);
    ushort_t* vT   = (ushort_t*)d_out;               // transposed v, per-batch [768][2048]
    float*  psums  = (float*)((char*)d_out + 25165824ll); // 2MB

    const int WQ = 0, WG1 = 1769472, WG2 = 2359296;
    const int BQ = 2949120, BG1 = 2951424, BG2 = 2952192, TSO = 2952960;

    const dim3 blk(256);
    const float scale = 0.03608439182435161f; // 1/sqrt(768)

    // 0. convert inputs + params to bf16 (single launch)
    convert_all<<<dim3(INBLK + (NTOT / 8 + 255) / 256), blk, 0, stream>>>(
        query, key_, value, Wq, Wk, Wv, Wg1, Wg2, bq, bk, bv, bg1, bg2, tsc, X, Wb);
    // 1. fused QKV projections: bz=0->q, 1->k, 2->vT (d_out, transposed write)
    gemm_bt<1, 0, 1><<<dim3(D / 128, MS / 128, 3), blk, 0, stream>>>(
        X, Wb + WQ, q, vT, Wb + BQ, nullptr, nullptr, nullptr,
        MS, D, D, 1.f, MSD, (long long)WSEG, MSD);
    // 2. P = exp(q @ k^T * scale), + per-block row partials -> psums (d_out tail); X dead
    gemm_bt<5, 0, 0><<<dim3(S / 128, S / 128, Bc), blk, 0, stream>>>(
        q, k, P, nullptr, nullptr, nullptr, nullptr, psums,
        S, S, D, scale, SD, SD, SS);
    // 3. att = (P @ vT^T) / rowsum   (rinv computed in-prologue from psums; att overlays q)
    gemm_bt<7, 0, 0><<<dim3(D / 128, S / 128, Bc), blk, 0, stream>>>(
        P, vT, att, nullptr, nullptr, nullptr, nullptr, psums,
        S, D, S, 1.f, SS, SD, SD);
    // 4. h = relu(att @ Wg1^T + bg1)  (h overlays k)
    gemm_bt<3, 0, 0><<<dim3(D / 128, MS / 128, 1), blk, 0, stream>>>(
        att, Wb + WG1, h, nullptr, Wb + BG1, nullptr, nullptr, nullptr,
        MS, D, D, 1.f, 0, 0, 0);
    // 5. out = sigmoid(sigmoid(h @ Wg2^T + bg2)) * att * ts  (f32 -> d_out, clobbers vT+psums)
    gemm_bt<4, 1, 0><<<dim3(D / 128, MS / 128, 1), blk, 0, stream>>>(
        h, Wb + WG2, d_out, nullptr, Wb + BG2, att, Wb + TSO, nullptr,
        MS, D, D, 1.f, 0, 0, 0);
}